// Round 12
// baseline (151.375 us; speedup 1.0000x reference)
//
#include <hip/hip_runtime.h>
#include <hip/hip_bf16.h>

// Shapes: x:(16,32,128) mask:(16,128) w1:(256,66) b1:(256) w2:(128,256) b2:(128) pool_w:(128,21)
// L=128, L2=16384, dim=256, out_c=128. Output (16,128) f32.

#define NB 16
#define CIN 33
#define DIM 256
#define LEN 128
#define OC 128
#define L2 16384

typedef short bf16x8 __attribute__((ext_vector_type(8)));
typedef float f32x4 __attribute__((ext_vector_type(4)));

__device__ __forceinline__ unsigned short f32_to_bf16_rne(float f) {
    unsigned u = __float_as_uint(f);
    unsigned rb = ((u >> 16) & 1u) + 0x7FFFu;
    return (unsigned short)((u + rb) >> 16);
}
__device__ __forceinline__ float bf16_to_f32(unsigned short b) {
    return __uint_as_float(((unsigned)b) << 16);
}
// two f32 -> packed bf16 pair (v_cvt_pk_bf16_f32), RNE
__device__ __forceinline__ unsigned pk_bf16(float a, float b) {
    __hip_bfloat162 p = __float22bfloat162_rn(make_float2(a, b));
    unsigned w;
    __builtin_memcpy(&w, &p, 4);
    return w;
}

// ---------------- kernel A: ha/hb = w1a/w1b @ xm, with b1 folded in (half each) ----------------
__global__ __launch_bounds__(128) void kA(const float* __restrict__ x,
                                          const float* __restrict__ mask,
                                          const float* __restrict__ w1,
                                          const float* __restrict__ b1,
                                          float* __restrict__ ha,
                                          float* __restrict__ hb) {
    int d = blockIdx.x;
    int n = blockIdx.y;
    int l = threadIdx.x;
    const float* w1r = w1 + d * (2 * CIN);
    float a = 0.f, b = 0.f;
#pragma unroll
    for (int c = 0; c < CIN; ++c) {
        float xv = (c < 32) ? x[((size_t)n * 32 + c) * LEN + l] : mask[(size_t)n * LEN + l];
        a = fmaf(w1r[c], xv, a);
        b = fmaf(w1r[CIN + c], xv, b);
    }
    float hb1 = 0.5f * b1[d];
    ha[((size_t)n * DIM + d) * LEN + l] = a + hb1;
    hb[((size_t)n * DIM + d) * LEN + l] = b + hb1;
}

// ---------------- kernel W: split w2 into bf16 hi/lo ----------------
__global__ __launch_bounds__(256) void kW(const float* __restrict__ w2,
                                          unsigned short* __restrict__ w2hi,
                                          unsigned short* __restrict__ w2lo) {
    int idx = blockIdx.x * 256 + threadIdx.x;   // 32768 total
    float v = w2[idx];
    unsigned short h = f32_to_bf16_rne(v);
    unsigned short l = f32_to_bf16_rne(v - bf16_to_f32(h));
    w2hi[idx] = h;
    w2lo[idx] = l;
}

// ---------------- kernel B: MFMA GEMM, split-bf16 A (from global), single-bf16 B ----------------
#define ROWP 40
__global__ __launch_bounds__(256) void kB(const float* __restrict__ ha,
                                          const float* __restrict__ hb,
                                          const unsigned short* __restrict__ w2hi,
                                          const unsigned short* __restrict__ w2lo,
                                          const float* __restrict__ b2,
                                          unsigned short* __restrict__ y,
                                          int nbase) {
    __shared__ unsigned short Bh[128 * ROWP];
    __shared__ float ha_s[DIM];
    int i0 = blockIdx.x;
    int zloc = blockIdx.y;
    int n = nbase + zloc;
    int tid = threadIdx.x;
    int wv = tid >> 6, l = tid & 63;
    int g = l >> 4, lr = l & 15;

    if (tid < DIM) ha_s[tid] = ha[((size_t)n * DIM + tid) * LEN + i0];

    f32x4 acc[2][8];
#pragma unroll
    for (int mt = 0; mt < 2; ++mt) {
        float bv[4];
#pragma unroll
        for (int r = 0; r < 4; ++r) bv[r] = b2[(wv * 2 + mt) * 16 + g * 4 + r];
#pragma unroll
        for (int nt = 0; nt < 8; ++nt)
#pragma unroll
            for (int r = 0; r < 4; ++r) acc[mt][nt][r] = bv[r];
    }

    const float* hbN = hb + (size_t)n * DIM * LEN;
    int j = tid & 127, kh = tid >> 7;
    __syncthreads();

    for (int d0 = 0; d0 < DIM; d0 += 32) {
        {
            union { unsigned w[8]; uint4 q[2]; } pkv;
#pragma unroll
            for (int kk = 0; kk < 16; kk += 2) {
                int d = d0 + kh * 16 + kk;
                float h0 = fmaxf(ha_s[d] + hbN[(size_t)d * LEN + j], 0.f);
                float h1 = fmaxf(ha_s[d + 1] + hbN[(size_t)(d + 1) * LEN + j], 0.f);
                pkv.w[kk >> 1] = pk_bf16(h0, h1);
            }
            *(uint4*)&Bh[j * ROWP + kh * 16] = pkv.q[0];
            *(uint4*)&Bh[j * ROWP + kh * 16 + 8] = pkv.q[1];
        }
        __syncthreads();

        bf16x8 ah[2], al[2];
#pragma unroll
        for (int mt = 0; mt < 2; ++mt) {
            int row = (wv * 2 + mt) * 16 + lr;
            ah[mt] = *(const bf16x8*)&w2hi[(size_t)row * DIM + d0 + g * 8];
            al[mt] = *(const bf16x8*)&w2lo[(size_t)row * DIM + d0 + g * 8];
        }
#pragma unroll
        for (int nt = 0; nt < 8; ++nt) {
            int brow = nt * 16 + lr;
            bf16x8 bh = *(bf16x8*)&Bh[brow * ROWP + g * 8];
#pragma unroll
            for (int mt = 0; mt < 2; ++mt) {
                acc[mt][nt] = __builtin_amdgcn_mfma_f32_16x16x32_bf16(ah[mt], bh, acc[mt][nt], 0, 0, 0);
                acc[mt][nt] = __builtin_amdgcn_mfma_f32_16x16x32_bf16(al[mt], bh, acc[mt][nt], 0, 0, 0);
            }
        }
        __syncthreads();
    }

#pragma unroll
    for (int mt = 0; mt < 2; ++mt)
#pragma unroll
        for (int nt = 0; nt < 8; ++nt)
#pragma unroll
            for (int r = 0; r < 4; ++r) {
                int o = (wv * 2 + mt) * 16 + g * 4 + r;
                int col = nt * 16 + lr;
                y[((size_t)zloc * OC + o) * L2 + (size_t)i0 * LEN + col] =
                    f32_to_bf16_rne(acc[mt][nt][r]);
            }
}

// ---------------- kernel C: histogram + per-BIN closed-form rank weighting ----------------
// 16384 count words (2 x u16 bins) + scratch (16 wave totals, 21 Wc, 21 pw) = 65,792 B LDS.
// Phase 2: ds_add histogram, no return. Phase 3: scan -> each thread walks its 32 bins;
// per occupied bin, contribution = val_mid * (W(hi)-W(lo)) with ONE chained closed-form
// W eval (piecewise-quadratic prefix of the reference's piecewise-linear w). No per-element
// pass, no scattered reads, no y re-read. Piece index = reference's own f32 formula (no loops);
// integer piece boundaries; boundary +/-1 mismatches are harmless (w continuous there).
__device__ __forceinline__ unsigned swz(unsigned w) { return w ^ ((w >> 2) & 0xCu); }

__device__ __forceinline__ float evalW(int R, const float* WcT, const float* pwT) {
    if (R <= 0) return 0.f;
    int rm1 = R - 1;
    float posf = fminf((float)rm1 * (1.0f / 16383.0f), 1.0f);
    int p = (int)(20.0f * posf);
    int a = (16383 * p + 19) / 20;           // first rank of piece p
    int N = R - a;
    long long M = (long long)N * (10LL * (a + R - 1) - 16383LL * p);  // 16383 * sum(frac)
    float dp = (p < 20) ? (pwT[p + 1] - pwT[p]) : 0.f;
    return WcT[p] + (float)N * pwT[p] + dp * (float)((double)M * (1.0 / 16383.0));
}

__device__ __forceinline__ float binval(int bin) {
    unsigned k0 = (unsigned)(bin << 1), k1 = k0 + 1;
    unsigned b0 = (k0 & 0x8000u) ? (k0 ^ 0x8000u) : (k0 ^ 0xFFFFu);
    unsigned b1 = (k1 & 0x8000u) ? (k1 ^ 0x8000u) : (k1 ^ 0xFFFFu);
    return 0.5f * (__uint_as_float(b0 << 16) + __uint_as_float(b1 << 16));
}

__global__ __launch_bounds__(1024, 8) void kC(const unsigned short* __restrict__ y,
                                              const float* __restrict__ pw,
                                              float* __restrict__ out,
                                              int nbase) {
    extern __shared__ unsigned hist[];   // 16384 + 64 words
    int row = blockIdx.x;
    int och = row & (OC - 1);
    int n = nbase + (row >> 7);
    int t = threadIdx.x;
    int lane = t & 63, wv = t >> 6;
    const unsigned short* yr = y + (size_t)row * L2;
    const float* pwo = pw + och * 21;
    int tsw = (t & 3) << 2;
    float* WcT = (float*)&hist[16384 + 16];
    float* pwT = (float*)&hist[16384 + 40];

    // 1. zero own 16 words
#pragma unroll
    for (int q = 0; q < 4; ++q)
        *(uint4*)&hist[t * 16 + ((q << 2) ^ tsw)] = make_uint4(0, 0, 0, 0);
    __syncthreads();

    // 2. histogram (no return needed -> ds_add)
    {
        union { uint4 q[2]; unsigned short u[16]; } ld;
        ld.q[0] = *(const uint4*)&yr[t * 16];
        ld.q[1] = *(const uint4*)&yr[t * 16 + 8];
#pragma unroll
        for (int e = 0; e < 16; ++e) {
            unsigned u = ld.u[e];
            unsigned k16 = u ^ ((u & 0x8000u) ? 0xFFFFu : 0x8000u);
            atomicAdd(&hist[swz(k16 >> 2)], ((k16 >> 1) & 1) ? 0x10000u : 1u);
        }
    }

    // 2b. wave 0: piece sums + exclusive scan -> Wc table; stage pw row
    if (wv == 0) {
        int p = lane;
        int a = (16383 * p + 19) / 20;
        int e2 = (p >= 20) ? L2 : (16383 * (p + 1) + 19) / 20;
        int N = e2 - a;
        float wp0 = (p <= 20) ? pwo[p] : 0.f;
        float wp1 = (p < 20) ? pwo[p + 1] : wp0;
        long long M = (long long)N * (10LL * (a + e2 - 1) - 16383LL * p);
        double ps = (double)N * (double)wp0 + (double)(wp1 - wp0) * ((double)M * (1.0 / 16383.0));
        double s = ps;
#pragma unroll
        for (int d = 1; d < 64; d <<= 1) {
            double u2 = __shfl_up(s, d, 64);
            if (lane >= d) s += u2;
        }
        if (p <= 20) {
            WcT[p] = (float)(s - ps);   // exclusive prefix
            pwT[p] = wp0;
        }
    }
    __syncthreads();

    // 3a. own-bin total + hierarchical exclusive prefix
    int Ti = 0;
#pragma unroll
    for (int q = 0; q < 4; ++q) {
        uint4 v4 = *(const uint4*)&hist[t * 16 + ((q << 2) ^ tsw)];
        Ti += (int)(v4.x & 0xFFFFu) + (int)(v4.x >> 16);
        Ti += (int)(v4.y & 0xFFFFu) + (int)(v4.y >> 16);
        Ti += (int)(v4.z & 0xFFFFu) + (int)(v4.z >> 16);
        Ti += (int)(v4.w & 0xFFFFu) + (int)(v4.w >> 16);
    }
    int incl = Ti;
#pragma unroll
    for (int d = 1; d < 64; d <<= 1) {
        int u2 = __shfl_up(incl, d, 64);
        if (lane >= d) incl += u2;
    }
    if (lane == 63) hist[16384 + wv] = (unsigned)incl;
    __syncthreads();
    int P = 0;
#pragma unroll
    for (int k = 0; k < 16; ++k) {
        int tw = (int)hist[16384 + k];
        P += (k < wv) ? tw : 0;
    }
    P += (incl - Ti);                    // ascending exclusive prefix before this thread's bins

    // 3b. walk own 32 bins (ascending): chained closed-form contributions
    float contrib = 0.f;
    float Wprev = evalW(L2 - P, WcT, pwT);
#pragma unroll
    for (int q = 0; q < 4; ++q) {
        uint4 v4 = *(const uint4*)&hist[t * 16 + ((q << 2) ^ tsw)];
        unsigned wd[4] = {v4.x, v4.y, v4.z, v4.w};
#pragma unroll
        for (int c4 = 0; c4 < 4; ++c4) {
            unsigned cw = wd[c4];
            if (cw) {
                int binb = (t * 16 + q * 4 + c4) * 2;
                int clo = (int)(cw & 0xFFFFu), chi = (int)(cw >> 16);
                if (clo) {
                    P += clo;
                    float Wn = evalW(L2 - P, WcT, pwT);
                    contrib = fmaf(binval(binb), Wprev - Wn, contrib);
                    Wprev = Wn;
                }
                if (chi) {
                    P += chi;
                    float Wn = evalW(L2 - P, WcT, pwT);
                    contrib = fmaf(binval(binb + 1), Wprev - Wn, contrib);
                    Wprev = Wn;
                }
            }
        }
    }

    // 4. reduce
#pragma unroll
    for (int d = 32; d >= 1; d >>= 1) contrib += __shfl_xor(contrib, d, 64);
    __syncthreads();
    if (lane == 0) ((float*)hist)[16384 + wv] = contrib;
    __syncthreads();
    if (t == 0) {
        double tot = 0.0;
#pragma unroll
        for (int k = 0; k < 16; ++k) tot += (double)((const float*)hist)[16384 + k];
        out[(size_t)n * OC + och] = (float)(tot * (1.0 / (double)L2));
    }
}

extern "C" void kernel_launch(void* const* d_in, const int* in_sizes, int n_in,
                              void* d_out, int out_size, void* d_ws, size_t ws_size,
                              hipStream_t stream) {
    const float* x    = (const float*)d_in[0];
    const float* mask = (const float*)d_in[1];
    const float* w1   = (const float*)d_in[2];
    const float* b1   = (const float*)d_in[3];
    const float* w2   = (const float*)d_in[4];
    const float* b2   = (const float*)d_in[5];
    const float* pw   = (const float*)d_in[6];
    float* out = (float*)d_out;

    char* ws = (char*)d_ws;
    float* ha = (float*)ws;                                       // 2 MB
    float* hb = ha + (size_t)NB * DIM * LEN;                      // 2 MB
    unsigned short* w2hi = (unsigned short*)(ws + (size_t)2 * NB * DIM * LEN * 4);  // 64 KB
    unsigned short* w2lo = w2hi + (size_t)OC * DIM;                                  // 64 KB
    unsigned short* y = w2lo + (size_t)OC * DIM;                  // up to 64 MB bf16

    size_t used = (size_t)2 * NB * DIM * LEN * 4 + (size_t)2 * OC * DIM * 2;
    size_t perN = (size_t)OC * L2 * 2;   // 4 MB per n (bf16)
    int nchunk = 1;
    if (ws_size > used + perN) {
        size_t c = (ws_size - used) / perN;
        nchunk = (int)(c > NB ? NB : c);
    }

    hipLaunchKernelGGL(kA, dim3(DIM, NB), dim3(128), 0, stream, x, mask, w1, b1, ha, hb);
    hipLaunchKernelGGL(kW, dim3(OC * DIM / 256), dim3(256), 0, stream, w2, w2hi, w2lo);
    for (int base = 0; base < NB; base += nchunk) {
        int nc = nchunk < (NB - base) ? nchunk : (NB - base);
        hipLaunchKernelGGL(kB, dim3(LEN, nc), dim3(256), 0, stream, ha, hb, w2hi, w2lo, b2, y, base);
        hipLaunchKernelGGL(kC, dim3(OC * nc), dim3(1024), (16384 + 64) * 4, stream, y, pw, out, base);
    }
}

// Round 14
// 145.981 us; speedup vs baseline: 1.0370x; 1.0370x over previous
//
#include <hip/hip_runtime.h>
#include <hip/hip_bf16.h>

// Shapes: x:(16,32,128) mask:(16,128) w1:(256,66) b1:(256) w2:(128,256) b2:(128) pool_w:(128,21)
// L=128, L2=16384, dim=256, out_c=128. Output (16,128) f32.

#define NB 16
#define CIN 33
#define DIM 256
#define LEN 128
#define OC 128
#define L2 16384

typedef short bf16x8 __attribute__((ext_vector_type(8)));
typedef float f32x4 __attribute__((ext_vector_type(4)));

__device__ __forceinline__ unsigned short f32_to_bf16_rne(float f) {
    unsigned u = __float_as_uint(f);
    unsigned rb = ((u >> 16) & 1u) + 0x7FFFu;
    return (unsigned short)((u + rb) >> 16);
}
__device__ __forceinline__ float bf16_to_f32(unsigned short b) {
    return __uint_as_float(((unsigned)b) << 16);
}
// two f32 -> packed bf16 pair (v_cvt_pk_bf16_f32), RNE
__device__ __forceinline__ unsigned pk_bf16(float a, float b) {
    __hip_bfloat162 p = __float22bfloat162_rn(make_float2(a, b));
    unsigned w;
    __builtin_memcpy(&w, &p, 4);
    return w;
}

// ---------------- kernel A: ha/hb = w1a/w1b @ xm, with b1 folded in (half each) ----------------
__global__ __launch_bounds__(128) void kA(const float* __restrict__ x,
                                          const float* __restrict__ mask,
                                          const float* __restrict__ w1,
                                          const float* __restrict__ b1,
                                          float* __restrict__ ha,
                                          float* __restrict__ hb) {
    int d = blockIdx.x;
    int n = blockIdx.y;
    int l = threadIdx.x;
    const float* w1r = w1 + d * (2 * CIN);
    float a = 0.f, b = 0.f;
#pragma unroll
    for (int c = 0; c < CIN; ++c) {
        float xv = (c < 32) ? x[((size_t)n * 32 + c) * LEN + l] : mask[(size_t)n * LEN + l];
        a = fmaf(w1r[c], xv, a);
        b = fmaf(w1r[CIN + c], xv, b);
    }
    float hb1 = 0.5f * b1[d];
    ha[((size_t)n * DIM + d) * LEN + l] = a + hb1;
    hb[((size_t)n * DIM + d) * LEN + l] = b + hb1;
}

// ---------------- kernel W: split w2 into bf16 hi/lo ----------------
__global__ __launch_bounds__(256) void kW(const float* __restrict__ w2,
                                          unsigned short* __restrict__ w2hi,
                                          unsigned short* __restrict__ w2lo) {
    int idx = blockIdx.x * 256 + threadIdx.x;   // 32768 total
    float v = w2[idx];
    unsigned short h = f32_to_bf16_rne(v);
    unsigned short l = f32_to_bf16_rne(v - bf16_to_f32(h));
    w2hi[idx] = h;
    w2lo[idx] = l;
}

// ---------------- kernel B: MFMA GEMM, split-bf16 A (from global), single-bf16 B ----------------
#define ROWP 40
__global__ __launch_bounds__(256) void kB(const float* __restrict__ ha,
                                          const float* __restrict__ hb,
                                          const unsigned short* __restrict__ w2hi,
                                          const unsigned short* __restrict__ w2lo,
                                          const float* __restrict__ b2,
                                          unsigned short* __restrict__ y,
                                          int nbase) {
    __shared__ unsigned short Bh[128 * ROWP];
    __shared__ float ha_s[DIM];
    int i0 = blockIdx.x;
    int zloc = blockIdx.y;
    int n = nbase + zloc;
    int tid = threadIdx.x;
    int wv = tid >> 6, l = tid & 63;
    int g = l >> 4, lr = l & 15;

    if (tid < DIM) ha_s[tid] = ha[((size_t)n * DIM + tid) * LEN + i0];

    f32x4 acc[2][8];
#pragma unroll
    for (int mt = 0; mt < 2; ++mt) {
        float bv[4];
#pragma unroll
        for (int r = 0; r < 4; ++r) bv[r] = b2[(wv * 2 + mt) * 16 + g * 4 + r];
#pragma unroll
        for (int nt = 0; nt < 8; ++nt)
#pragma unroll
            for (int r = 0; r < 4; ++r) acc[mt][nt][r] = bv[r];
    }

    const float* hbN = hb + (size_t)n * DIM * LEN;
    int j = tid & 127, kh = tid >> 7;
    __syncthreads();

    for (int d0 = 0; d0 < DIM; d0 += 32) {
        {
            union { unsigned w[8]; uint4 q[2]; } pkv;
#pragma unroll
            for (int kk = 0; kk < 16; kk += 2) {
                int d = d0 + kh * 16 + kk;
                float h0 = fmaxf(ha_s[d] + hbN[(size_t)d * LEN + j], 0.f);
                float h1 = fmaxf(ha_s[d + 1] + hbN[(size_t)(d + 1) * LEN + j], 0.f);
                pkv.w[kk >> 1] = pk_bf16(h0, h1);
            }
            *(uint4*)&Bh[j * ROWP + kh * 16] = pkv.q[0];
            *(uint4*)&Bh[j * ROWP + kh * 16 + 8] = pkv.q[1];
        }
        __syncthreads();

        bf16x8 ah[2], al[2];
#pragma unroll
        for (int mt = 0; mt < 2; ++mt) {
            int row = (wv * 2 + mt) * 16 + lr;
            ah[mt] = *(const bf16x8*)&w2hi[(size_t)row * DIM + d0 + g * 8];
            al[mt] = *(const bf16x8*)&w2lo[(size_t)row * DIM + d0 + g * 8];
        }
#pragma unroll
        for (int nt = 0; nt < 8; ++nt) {
            int brow = nt * 16 + lr;
            bf16x8 bh = *(bf16x8*)&Bh[brow * ROWP + g * 8];
#pragma unroll
            for (int mt = 0; mt < 2; ++mt) {
                acc[mt][nt] = __builtin_amdgcn_mfma_f32_16x16x32_bf16(ah[mt], bh, acc[mt][nt], 0, 0, 0);
                acc[mt][nt] = __builtin_amdgcn_mfma_f32_16x16x32_bf16(al[mt], bh, acc[mt][nt], 0, 0, 0);
            }
        }
        __syncthreads();
    }

#pragma unroll
    for (int mt = 0; mt < 2; ++mt)
#pragma unroll
        for (int nt = 0; nt < 8; ++nt)
#pragma unroll
            for (int r = 0; r < 4; ++r) {
                int o = (wv * 2 + mt) * 16 + g * 4 + r;
                int col = nt * 16 + lr;
                y[((size_t)zloc * OC + o) * L2 + (size_t)i0 * LEN + col] =
                    f32_to_bf16_rne(acc[mt][nt][r]);
            }
}

// ---------------- kernel C: histogram + per-BIN closed-form rank weighting ----------------
// ANTI-CORRELATED PAIRING: word w holds bin w (lo half) and bin w+16384 (hi half).
// Adjacent bins -> adjacent words/banks; paired bins are value-opposite (uncorrelated).
// Scan: packed (lo | hi<<16) shfl prefix (each half <= 16384, no carry), then two chained
// per-bin walks (lo bins, then hi bins offset by the GLOBAL lo total).
__device__ __forceinline__ unsigned swz(unsigned w) { return w ^ ((w >> 2) & 0xCu); }

__device__ __forceinline__ float evalW(int R, const float* WcT, const float* pwT) {
    if (R <= 0) return 0.f;
    int rm1 = R - 1;
    float posf = fminf((float)rm1 * (1.0f / 16383.0f), 1.0f);
    int p = (int)(20.0f * posf);
    int a = (16383 * p + 19) / 20;           // first rank of piece p
    int N = R - a;
    long long M = (long long)N * (10LL * (a + R - 1) - 16383LL * p);  // 16383 * sum(frac)
    float dp = (p < 20) ? (pwT[p + 1] - pwT[p]) : 0.f;
    return WcT[p] + (float)N * pwT[p] + dp * (float)((double)M * (1.0 / 16383.0));
}

__device__ __forceinline__ float binval(int bin) {   // bin in [0, 32768)
    unsigned k0 = (unsigned)(bin << 1), k1 = k0 + 1;
    unsigned b0 = (k0 & 0x8000u) ? (k0 ^ 0x8000u) : (k0 ^ 0xFFFFu);
    unsigned b1 = (k1 & 0x8000u) ? (k1 ^ 0x8000u) : (k1 ^ 0xFFFFu);
    return 0.5f * (__uint_as_float(b0 << 16) + __uint_as_float(b1 << 16));
}

__global__ __launch_bounds__(1024, 8) void kC(const unsigned short* __restrict__ y,
                                              const float* __restrict__ pw,
                                              float* __restrict__ out,
                                              int nbase) {
    extern __shared__ unsigned hist[];   // 16384 + 64 words
    int row = blockIdx.x;
    int och = row & (OC - 1);
    int n = nbase + (row >> 7);
    int t = threadIdx.x;
    int lane = t & 63, wv = t >> 6;
    const unsigned short* yr = y + (size_t)row * L2;
    const float* pwo = pw + och * 21;
    int tsw = (t & 3) << 2;
    float* WcT = (float*)&hist[16384 + 16];
    float* pwT = (float*)&hist[16384 + 40];

    // 1. zero own 16 words
#pragma unroll
    for (int q = 0; q < 4; ++q)
        *(uint4*)&hist[t * 16 + ((q << 2) ^ tsw)] = make_uint4(0, 0, 0, 0);
    __syncthreads();

    // 2. histogram: bin = k16>>1 in [0,32768); word = bin & 16383; unit = (bin>>14)? hi : lo.
    {
        union { uint4 q[2]; unsigned short u[16]; } ld;
        ld.q[0] = *(const uint4*)&yr[t * 16];
        ld.q[1] = *(const uint4*)&yr[t * 16 + 8];
#pragma unroll
        for (int e = 0; e < 16; e += 2) {
            unsigned u0 = ld.u[e], u1 = ld.u[e + 1];
            unsigned k0 = u0 ^ ((u0 & 0x8000u) ? 0xFFFFu : 0x8000u);
            unsigned k1 = u1 ^ ((u1 & 0x8000u) ? 0xFFFFu : 0x8000u);
            unsigned b0 = k0 >> 1, b1 = k1 >> 1;
            unsigned w0 = b0 & 16383u, w1 = b1 & 16383u;
            unsigned un0 = (b0 >> 14) ? 0x10000u : 1u;
            unsigned un1 = (b1 >> 14) ? 0x10000u : 1u;
            if (w0 == w1) {
                atomicAdd(&hist[swz(w0)], un0 + un1);
            } else {
                atomicAdd(&hist[swz(w0)], un0);
                atomicAdd(&hist[swz(w1)], un1);
            }
        }
    }

    // 2b. wave 0: piece sums + exclusive scan -> Wc table; stage pw row
    if (wv == 0) {
        int p = lane;
        int a = (16383 * p + 19) / 20;
        int e2 = (p >= 20) ? L2 : (16383 * (p + 1) + 19) / 20;
        int N = e2 - a;
        float wp0 = (p <= 20) ? pwo[p] : 0.f;
        float wp1 = (p < 20) ? pwo[p + 1] : wp0;
        long long M = (long long)N * (10LL * (a + e2 - 1) - 16383LL * p);
        double ps = (double)N * (double)wp0 + (double)(wp1 - wp0) * ((double)M * (1.0 / 16383.0));
        double s = ps;
#pragma unroll
        for (int d = 1; d < 64; d <<= 1) {
            double u2 = __shfl_up(s, d, 64);
            if (lane >= d) s += u2;
        }
        if (p <= 20) {
            WcT[p] = (float)(s - ps);   // exclusive prefix
            pwT[p] = wp0;
        }
    }
    __syncthreads();

    // 3a. own totals, packed (lo | hi<<16); hierarchical exclusive prefix (packed, no carry)
    unsigned Tp = 0;
#pragma unroll
    for (int q = 0; q < 4; ++q) {
        uint4 v4 = *(const uint4*)&hist[t * 16 + ((q << 2) ^ tsw)];
        Tp += (v4.x & 0xFFFFu) + (v4.x & 0xFFFF0000u);
        Tp += (v4.y & 0xFFFFu) + (v4.y & 0xFFFF0000u);
        Tp += (v4.z & 0xFFFFu) + (v4.z & 0xFFFF0000u);
        Tp += (v4.w & 0xFFFFu) + (v4.w & 0xFFFF0000u);
    }
    unsigned incl = Tp;
#pragma unroll
    for (int d = 1; d < 64; d <<= 1) {
        unsigned u2 = __shfl_up(incl, d, 64);
        if (lane >= d) incl += u2;
    }
    if (lane == 63) hist[16384 + wv] = incl;
    __syncthreads();
    unsigned Pp = 0, Sall = 0;
#pragma unroll
    for (int k = 0; k < 16; ++k) {
        unsigned tw = hist[16384 + k];     // per-wave packed totals
        Sall += tw;                        // global packed total
        Pp += (k < wv) ? tw : 0;           // packed base before this wave
    }
    unsigned TotalLo = Sall & 0xFFFFu;     // GLOBAL lo-bin count (bug fix vs R12)
    Pp += incl - Tp;                       // packed exclusive prefix before this thread's words

    // 3b. walk lo bins [16t,16t+16) then hi bins [16384+16t, ...): chained closed-form W
    float contrib = 0.f;
    {
        int P = (int)(Pp & 0xFFFFu);
        float Wprev = evalW(L2 - P, WcT, pwT);
#pragma unroll
        for (int q = 0; q < 4; ++q) {
            uint4 v4 = *(const uint4*)&hist[t * 16 + ((q << 2) ^ tsw)];
            unsigned wd[4] = {v4.x, v4.y, v4.z, v4.w};
#pragma unroll
            for (int c4 = 0; c4 < 4; ++c4) {
                int c = (int)(wd[c4] & 0xFFFFu);
                if (c) {
                    P += c;
                    float Wn = evalW(L2 - P, WcT, pwT);
                    contrib = fmaf(binval(t * 16 + q * 4 + c4), Wprev - Wn, contrib);
                    Wprev = Wn;
                }
            }
        }
        int P2 = (int)TotalLo + (int)(Pp >> 16);
        float Wprev2 = evalW(L2 - P2, WcT, pwT);
#pragma unroll
        for (int q = 0; q < 4; ++q) {
            uint4 v4 = *(const uint4*)&hist[t * 16 + ((q << 2) ^ tsw)];
            unsigned wd[4] = {v4.x, v4.y, v4.z, v4.w};
#pragma unroll
            for (int c4 = 0; c4 < 4; ++c4) {
                int c = (int)(wd[c4] >> 16);
                if (c) {
                    P2 += c;
                    float Wn = evalW(L2 - P2, WcT, pwT);
                    contrib = fmaf(binval(16384 + t * 16 + q * 4 + c4), Wprev2 - Wn, contrib);
                    Wprev2 = Wn;
                }
            }
        }
    }

    // 4. reduce
#pragma unroll
    for (int d = 32; d >= 1; d >>= 1) contrib += __shfl_xor(contrib, d, 64);
    __syncthreads();
    if (lane == 0) ((float*)hist)[16384 + wv] = contrib;
    __syncthreads();
    if (t == 0) {
        double tot = 0.0;
#pragma unroll
        for (int k = 0; k < 16; ++k) tot += (double)((const float*)hist)[16384 + k];
        out[(size_t)n * OC + och] = (float)(tot * (1.0 / (double)L2));
    }
}

extern "C" void kernel_launch(void* const* d_in, const int* in_sizes, int n_in,
                              void* d_out, int out_size, void* d_ws, size_t ws_size,
                              hipStream_t stream) {
    const float* x    = (const float*)d_in[0];
    const float* mask = (const float*)d_in[1];
    const float* w1   = (const float*)d_in[2];
    const float* b1   = (const float*)d_in[3];
    const float* w2   = (const float*)d_in[4];
    const float* b2   = (const float*)d_in[5];
    const float* pw   = (const float*)d_in[6];
    float* out = (float*)d_out;

    char* ws = (char*)d_ws;
    float* ha = (float*)ws;                                       // 2 MB
    float* hb = ha + (size_t)NB * DIM * LEN;                      // 2 MB
    unsigned short* w2hi = (unsigned short*)(ws + (size_t)2 * NB * DIM * LEN * 4);  // 64 KB
    unsigned short* w2lo = w2hi + (size_t)OC * DIM;                                  // 64 KB
    unsigned short* y = w2lo + (size_t)OC * DIM;                  // up to 64 MB bf16

    size_t used = (size_t)2 * NB * DIM * LEN * 4 + (size_t)2 * OC * DIM * 2;
    size_t perN = (size_t)OC * L2 * 2;   // 4 MB per n (bf16)
    int nchunk = 1;
    if (ws_size > used + perN) {
        size_t c = (ws_size - used) / perN;
        nchunk = (int)(c > NB ? NB : c);
    }

    hipLaunchKernelGGL(kA, dim3(DIM, NB), dim3(128), 0, stream, x, mask, w1, b1, ha, hb);
    hipLaunchKernelGGL(kW, dim3(OC * DIM / 256), dim3(256), 0, stream, w2, w2hi, w2lo);
    for (int base = 0; base < NB; base += nchunk) {
        int nc = nchunk < (NB - base) ? nchunk : (NB - base);
        hipLaunchKernelGGL(kB, dim3(LEN, nc), dim3(256), 0, stream, ha, hb, w2hi, w2lo, b2, y, base);
        hipLaunchKernelGGL(kC, dim3(OC * nc), dim3(1024), (16384 + 64) * 4, stream, y, pw, out, base);
    }
}